// Round 7
// baseline (112.815 us; speedup 1.0000x reference)
//
#include <hip/hip_runtime.h>

// topk_mean pooling (k=2), single fused kernel. patch_ids are SORTED along
// seq, so each patch is a contiguous token run. One block (128 thr) per
// (b,p) pair.
//
// Boundary discovery WITHOUT dependent-load chains: lower_bound_b(p) is
// Binomial(seq, p/P) => mean seq*p/P, sigma <= 32 (seq=4096, P=1024). Each
// block loads a 257-entry pid window centered on the estimate (+-128 = 4
// sigma) with ONE coalesced load, then finds both boundaries by LDS scan:
//   j = lower_bound(t) is the unique local pos i with swin[i-1] < t <= swin[i]
// (INT_MAX padding past seq makes j==seq a normal in-window hit; j==0 is the
// w0==0 edge). P(out-of-window) ~ 1e-4/block -> rare fallback binary search
// (also covers a boundary landing exactly at w0 with w0>0).
//
// THIS ROUND's single isolated change vs the verified 106.6us kernel:
// nontemporal (nt) loads for h rows and nt stores for out. Both are strictly
// single-touch per iteration (the harness's 268MB poison fills flush caches
// every iteration), while the pid windows ARE reused (~1024 blocks/row) and
// should stay L2-hot -> keep pid loads cached, bypass allocate for h/out.
// nt builtins need native clang vectors -> vf4 ext_vector for h/out.
//
// Pool body otherwise identical: token loop prefetches up to D=8 rows before
// consuming => single HBM latency exposure for n<=8 (tokens/patch~Poisson(4)).
//
// Semantics (faithful to reference): m1 = max over run; m2 = max over values
// STRICTLY below m1 (reference masks ALL copies of the max with -1e9);
//   n==0 -> 0 ; n==1 or k==1 -> m1 ; n>=2 -> 0.5*(m1 + max(m2, -1e9)).

#define NEG_INF (-1.0e9f)
#define D 8     // prefetch depth: independent row loads in flight per thread
#define W 256   // speculative pid window (2 * 4 sigma); block loads W+1 ints

typedef float vf4 __attribute__((ext_vector_type(4)));

__global__ __launch_bounds__(128) void topk_mean_pool_win(
    const float* __restrict__ h,
    const int*   __restrict__ pid,
    const int*   __restrict__ d_P,
    const int*   __restrict__ d_k,
    float*       __restrict__ out,
    int bs_seq, int pairs, int E)
{
    const int P   = *d_P;
    const int bs  = pairs / P;
    const int seq = bs_seq / bs;
    const int kk  = *d_k;

    const int pair = blockIdx.x;     // pair = b*P + p
    const int b    = pair / P;
    const int p    = pair - b * P;

    __shared__ int swin[W + 1];
    __shared__ int sb[2];            // sb[0]=lower_bound(p), sb[1]=lower_bound(p+1)

    const int* row = pid + (size_t)b * seq;

    // Window start (block-uniform), centered on expected lower_bound(p).
    int w0 = (int)(((long long)seq * p) / P) - W / 2;
    if (w0 < 0) w0 = 0;
    if (w0 > seq - W) w0 = seq - W;
    if (w0 < 0) w0 = 0;              // degenerate seq < W

    if (threadIdx.x < 2) sb[threadIdx.x] = -1;
    {   // one coalesced load of W+1 pid values, INT_MAX-padded past seq
        const int i0 = threadIdx.x, i1 = threadIdx.x + 128;
        const int g0 = w0 + i0, g1 = w0 + i1;
        swin[i0] = (g0 < seq) ? row[g0] : 0x7fffffff;
        swin[i1] = (g1 < seq) ? row[g1] : 0x7fffffff;
        if (threadIdx.x == 0) {
            const int g2 = w0 + W;
            swin[W] = (g2 < seq) ? row[g2] : 0x7fffffff;
        }
    }
    __syncthreads();

    // Unique-writer detection (sorted row => exactly one position matches).
#pragma unroll
    for (int x = 0; x < 2; ++x) {
        const int t  = p + x;
        const int i0 = threadIdx.x + 1;     // covers local pos 1..128
        const int i1 = threadIdx.x + 129;   // covers local pos 129..256
        if (swin[i0 - 1] < t && swin[i0] >= t) sb[x] = w0 + i0;
        if (swin[i1 - 1] < t && swin[i1] >= t) sb[x] = w0 + i1;
        if (threadIdx.x == 0 && w0 == 0 && swin[0] >= t) sb[x] = 0;
    }
    __syncthreads();

    // Rare fallback (boundary fell outside the 4-sigma window or at w0>0).
    if (threadIdx.x < 2 && sb[threadIdx.x] < 0) {
        const int t = p + (int)threadIdx.x;
        int lo = 0, hi = seq;
        while (lo < hi) {
            const int mid = (lo + hi) >> 1;
            if (row[mid] < t) lo = mid + 1; else hi = mid;
        }
        sb[threadIdx.x] = lo;
    }
    __syncthreads();

    const int start = sb[0];
    const int end   = sb[1];
    const int n     = end - start;

    const int Ed4 = E >> 2;          // 128 for E=512
    const vf4* hb   = reinterpret_cast<const vf4*>(h) + (size_t)b * seq * Ed4;
    vf4*       out4 = reinterpret_cast<vf4*>(out) + (size_t)pair * Ed4;

    for (int c = threadIdx.x; c < Ed4; c += blockDim.x) {
        vf4 r;
        if (n == 0) {
            r = (vf4){0.f, 0.f, 0.f, 0.f};
        } else {
            vf4 m1 = (vf4){-INFINITY, -INFINITY, -INFINITY, -INFINITY};
            vf4 m2 = m1;
            int t = start;
            while (t < end) {
                const int nload = min(D, end - t);
                vf4 v[D];
                // issue all chunk loads before consuming any -> one latency
                // exposure per chunk (n<=8: one exposure total)
#pragma unroll
                for (int d = 0; d < D; ++d)
                    if (d < nload)
                        v[d] = __builtin_nontemporal_load(
                                   &hb[(size_t)(t + d) * Ed4 + c]);
#pragma unroll
                for (int d = 0; d < D; ++d) {
                    if (d < nload) {
                        const vf4 vv = v[d];
                        if (vv.x > m1.x) { m2.x = m1.x; m1.x = vv.x; }
                        else if (vv.x < m1.x && vv.x > m2.x) { m2.x = vv.x; }
                        if (vv.y > m1.y) { m2.y = m1.y; m1.y = vv.y; }
                        else if (vv.y < m1.y && vv.y > m2.y) { m2.y = vv.y; }
                        if (vv.z > m1.z) { m2.z = m1.z; m1.z = vv.z; }
                        else if (vv.z < m1.z && vv.z > m2.z) { m2.z = vv.z; }
                        if (vv.w > m1.w) { m2.w = m1.w; m1.w = vv.w; }
                        else if (vv.w < m1.w && vv.w > m2.w) { m2.w = vv.w; }
                    }
                }
                t += nload;
            }
            if (n == 1 || kk == 1) {
                r = m1;
            } else {
                r.x = 0.5f * (m1.x + fmaxf(m2.x, NEG_INF));
                r.y = 0.5f * (m1.y + fmaxf(m2.y, NEG_INF));
                r.z = 0.5f * (m1.z + fmaxf(m2.z, NEG_INF));
                r.w = 0.5f * (m1.w + fmaxf(m2.w, NEG_INF));
            }
        }
        __builtin_nontemporal_store(r, &out4[c]);
    }
}

extern "C" void kernel_launch(void* const* d_in, const int* in_sizes, int n_in,
                              void* d_out, int out_size, void* d_ws, size_t ws_size,
                              hipStream_t stream) {
    const float* h   = (const float*)d_in[0];
    const int*   pid = (const int*)d_in[1];
    const int*   d_P = (const int*)d_in[2];
    const int*   d_k = (const int*)d_in[3];
    float*       out = (float*)d_out;
    (void)d_ws; (void)ws_size; (void)n_in;

    const int h_elems = in_sizes[0];       // bs*seq*E
    const int bs_seq  = in_sizes[1];       // bs*seq
    const int E       = h_elems / bs_seq;  // 512
    const int pairs   = out_size / E;      // bs*P

    dim3 grid(pairs), block(128);
    topk_mean_pool_win<<<grid, block, 0, stream>>>(h, pid, d_P, d_k, out,
                                                   bs_seq, pairs, E);
}

// Round 8
// 106.388 us; speedup vs baseline: 1.0604x; 1.0604x over previous
//
#include <hip/hip_runtime.h>

// topk_mean pooling (k=2), single fused kernel. patch_ids are SORTED along
// seq, so each patch is a contiguous token run. One block (128 thr) per
// (b,p) pair.
//
// Boundary discovery WITHOUT dependent-load chains: lower_bound_b(p) is
// Binomial(seq, p/P) => mean seq*p/P, sigma <= 32 (seq=4096, P=1024). Each
// block loads a 257-entry pid window centered on the estimate (+-128 = 4
// sigma) with ONE coalesced load, then finds both boundaries by LDS scan:
//   j = lower_bound(t) is the unique local pos i with swin[i-1] < t <= swin[i]
// (INT_MAX padding past seq makes j==seq a normal in-window hit; j==0 is the
// w0==0 edge). P(out-of-window) ~ 1e-4/block -> rare fallback binary search
// (also covers a boundary landing exactly at w0 with w0>0).
//
// BEST VERIFIED VERSION (round 6, 106.6us). Round-7's nontemporal h/out
// variant regressed to 112.8us (nt bypasses L2 allocate; concurrent blocks
// share h cache lines/DRAM pages, so losing allocate/merge cost more than
// the posited pollution saved). Plain cached float4 accesses stand.
//
// Pool body: token loop prefetches up to D=8 rows before consuming =>
// single HBM latency exposure for n<=8 (tokens/patch ~ Poisson(4)).
//
// Semantics (faithful to reference): m1 = max over run; m2 = max over values
// STRICTLY below m1 (reference masks ALL copies of the max with -1e9);
//   n==0 -> 0 ; n==1 or k==1 -> m1 ; n>=2 -> 0.5*(m1 + max(m2, -1e9)).

#define NEG_INF (-1.0e9f)
#define D 8     // prefetch depth: independent row loads in flight per thread
#define W 256   // speculative pid window (2 * 4 sigma); block loads W+1 ints

__global__ __launch_bounds__(128) void topk_mean_pool_win(
    const float* __restrict__ h,
    const int*   __restrict__ pid,
    const int*   __restrict__ d_P,
    const int*   __restrict__ d_k,
    float*       __restrict__ out,
    int bs_seq, int pairs, int E)
{
    const int P   = *d_P;
    const int bs  = pairs / P;
    const int seq = bs_seq / bs;
    const int kk  = *d_k;

    const int pair = blockIdx.x;     // pair = b*P + p
    const int b    = pair / P;
    const int p    = pair - b * P;

    __shared__ int swin[W + 1];
    __shared__ int sb[2];            // sb[0]=lower_bound(p), sb[1]=lower_bound(p+1)

    const int* row = pid + (size_t)b * seq;

    // Window start (block-uniform), centered on expected lower_bound(p).
    int w0 = (int)(((long long)seq * p) / P) - W / 2;
    if (w0 < 0) w0 = 0;
    if (w0 > seq - W) w0 = seq - W;
    if (w0 < 0) w0 = 0;              // degenerate seq < W

    if (threadIdx.x < 2) sb[threadIdx.x] = -1;
    {   // one coalesced load of W+1 pid values, INT_MAX-padded past seq
        const int i0 = threadIdx.x, i1 = threadIdx.x + 128;
        const int g0 = w0 + i0, g1 = w0 + i1;
        swin[i0] = (g0 < seq) ? row[g0] : 0x7fffffff;
        swin[i1] = (g1 < seq) ? row[g1] : 0x7fffffff;
        if (threadIdx.x == 0) {
            const int g2 = w0 + W;
            swin[W] = (g2 < seq) ? row[g2] : 0x7fffffff;
        }
    }
    __syncthreads();

    // Unique-writer detection (sorted row => exactly one position matches).
#pragma unroll
    for (int x = 0; x < 2; ++x) {
        const int t  = p + x;
        const int i0 = threadIdx.x + 1;     // covers local pos 1..128
        const int i1 = threadIdx.x + 129;   // covers local pos 129..256
        if (swin[i0 - 1] < t && swin[i0] >= t) sb[x] = w0 + i0;
        if (swin[i1 - 1] < t && swin[i1] >= t) sb[x] = w0 + i1;
        if (threadIdx.x == 0 && w0 == 0 && swin[0] >= t) sb[x] = 0;
    }
    __syncthreads();

    // Rare fallback (boundary fell outside the 4-sigma window or at w0>0).
    if (threadIdx.x < 2 && sb[threadIdx.x] < 0) {
        const int t = p + (int)threadIdx.x;
        int lo = 0, hi = seq;
        while (lo < hi) {
            const int mid = (lo + hi) >> 1;
            if (row[mid] < t) lo = mid + 1; else hi = mid;
        }
        sb[threadIdx.x] = lo;
    }
    __syncthreads();

    const int start = sb[0];
    const int end   = sb[1];
    const int n     = end - start;

    const int Ed4 = E >> 2;          // 128 for E=512
    const float4* hb   = (const float4*)h + (size_t)b * seq * Ed4;
    float4*       out4 = (float4*)out + (size_t)pair * Ed4;

    for (int c = threadIdx.x; c < Ed4; c += blockDim.x) {
        float4 r;
        if (n == 0) {
            r = make_float4(0.f, 0.f, 0.f, 0.f);
        } else {
            float4 m1 = make_float4(-INFINITY, -INFINITY, -INFINITY, -INFINITY);
            float4 m2 = m1;
            int t = start;
            while (t < end) {
                const int nload = min(D, end - t);
                float4 v[D];
                // issue all chunk loads before consuming any -> one latency
                // exposure per chunk (n<=8: one exposure total)
#pragma unroll
                for (int d = 0; d < D; ++d)
                    if (d < nload) v[d] = hb[(size_t)(t + d) * Ed4 + c];
#pragma unroll
                for (int d = 0; d < D; ++d) {
                    if (d < nload) {
                        const float4 vv = v[d];
                        if (vv.x > m1.x) { m2.x = m1.x; m1.x = vv.x; }
                        else if (vv.x < m1.x && vv.x > m2.x) { m2.x = vv.x; }
                        if (vv.y > m1.y) { m2.y = m1.y; m1.y = vv.y; }
                        else if (vv.y < m1.y && vv.y > m2.y) { m2.y = vv.y; }
                        if (vv.z > m1.z) { m2.z = m1.z; m1.z = vv.z; }
                        else if (vv.z < m1.z && vv.z > m2.z) { m2.z = vv.z; }
                        if (vv.w > m1.w) { m2.w = m1.w; m1.w = vv.w; }
                        else if (vv.w < m1.w && vv.w > m2.w) { m2.w = vv.w; }
                    }
                }
                t += nload;
            }
            if (n == 1 || kk == 1) {
                r = m1;
            } else {
                r.x = 0.5f * (m1.x + fmaxf(m2.x, NEG_INF));
                r.y = 0.5f * (m1.y + fmaxf(m2.y, NEG_INF));
                r.z = 0.5f * (m1.z + fmaxf(m2.z, NEG_INF));
                r.w = 0.5f * (m1.w + fmaxf(m2.w, NEG_INF));
            }
        }
        out4[c] = r;
    }
}

extern "C" void kernel_launch(void* const* d_in, const int* in_sizes, int n_in,
                              void* d_out, int out_size, void* d_ws, size_t ws_size,
                              hipStream_t stream) {
    const float* h   = (const float*)d_in[0];
    const int*   pid = (const int*)d_in[1];
    const int*   d_P = (const int*)d_in[2];
    const int*   d_k = (const int*)d_in[3];
    float*       out = (float*)d_out;
    (void)d_ws; (void)ws_size; (void)n_in;

    const int h_elems = in_sizes[0];       // bs*seq*E
    const int bs_seq  = in_sizes[1];       // bs*seq
    const int E       = h_elems / bs_seq;  // 512
    const int pairs   = out_size / E;      // bs*P

    dim3 grid(pairs), block(128);
    topk_mean_pool_win<<<grid, block, 0, stream>>>(h, pid, d_P, d_k, out,
                                                   bs_seq, pairs, E);
}